// Round 8
// baseline (552.815 us; speedup 1.0000x reference)
//
#include <hip/hip_runtime.h>

#define DEVI __device__ __forceinline__

typedef __attribute__((ext_vector_type(8))) short bf16x8;
typedef __attribute__((ext_vector_type(4))) float f32x4;
typedef __attribute__((ext_vector_type(16))) float f32x16;

#define SQL 4096
#define DM 1024
#define NH 16
#define HD 64
#define S64 (SQL * HD)  // per-head plane elems

// ---------- helpers ----------
DEVI unsigned short f2bf(float f) {
  unsigned int u = __float_as_uint(f);
  unsigned int r = (u + 0x7FFFu + ((u >> 16) & 1u)) >> 16;
  return (unsigned short)r;
}

DEVI void gl16(const void* g, void* l) {
  __builtin_amdgcn_global_load_lds((const __attribute__((address_space(1))) void*)g,
                                   (__attribute__((address_space(3))) void*)l, 16, 0, 0);
}

DEVI f32x4 mfma16(bf16x8 a, bf16x8 b, f32x4 c) {
  return __builtin_amdgcn_mfma_f32_16x16x32_bf16(a, b, c, 0, 0, 0);
}
DEVI f32x16 mfma32(bf16x8 a, bf16x8 b, f32x16 c) {
  return __builtin_amdgcn_mfma_f32_32x32x16_bf16(a, b, c, 0, 0, 0);
}

DEVI unsigned cvtpk(float lo, float hi) {
  unsigned r;
  asm("v_cvt_pk_bf16_f32 %0, %1, %2" : "=v"(r) : "v"(lo), "v"(hi));
  return r;
}

DEVI bf16x8 ld_b64x2(const char* p) {
  union { uint2 u[2]; bf16x8 v; } x;
  x.u[0] = *(const uint2*)p;
  x.u[1] = *(const uint2*)(p + 8);
  return x.v;
}

// ---------- fused fp32 -> bf16 convert (7 tensors, 1 dispatch) ----------
__global__ void cvt_all(const float* __restrict__ q, const float* __restrict__ k,
                        const float* __restrict__ v, const float* __restrict__ Wq,
                        const float* __restrict__ Wk, const float* __restrict__ Wv,
                        const float* __restrict__ Wo, unsigned short* __restrict__ o) {
  const size_t SD = (size_t)SQL * DM, DD = (size_t)DM * DM;
  size_t i = ((size_t)blockIdx.x * 256 + threadIdx.x) * 4;
  const float* src;
  size_t base;
  if (i < SD) { src = q; base = 0; }
  else if (i < 2 * SD) { src = k; base = SD; }
  else if (i < 3 * SD) { src = v; base = 2 * SD; }
  else if (i < 3 * SD + DD) { src = Wq; base = 3 * SD; }
  else if (i < 3 * SD + 2 * DD) { src = Wk; base = 3 * SD + DD; }
  else if (i < 3 * SD + 3 * DD) { src = Wv; base = 3 * SD + 2 * DD; }
  else { src = Wo; base = 3 * SD + 3 * DD; }
  float4 vv = *reinterpret_cast<const float4*>(src + (i - base));
  ushort4 ov;
  ov.x = f2bf(vv.x); ov.y = f2bf(vv.y); ov.z = f2bf(vv.z); ov.w = f2bf(vv.w);
  *reinterpret_cast<ushort4*>(o + i) = ov;
}

// ---------- batched QKV GEMM ----------
// z=0 -> Qh [h][s][d] scaled by 0.125*log2(e); z=1 -> Kh [h][s][d];
// z=2 -> VT [h][d][s] via LDS transpose (coalesced stores)
__global__ __launch_bounds__(256) void gemm_qkv(
    const unsigned short* __restrict__ xq, const unsigned short* __restrict__ xk,
    const unsigned short* __restrict__ xv, const unsigned short* __restrict__ wq,
    const unsigned short* __restrict__ wk, const unsigned short* __restrict__ wv,
    const float* __restrict__ bq, const float* __restrict__ bk, const float* __restrict__ bv,
    unsigned short* __restrict__ Qh, unsigned short* __restrict__ Kh,
    unsigned short* __restrict__ VT) {
  __shared__ __align__(16) unsigned short smem[17408];  // lA(8192) + lB(8192); z=2: [128][136]
  unsigned short* lA = smem;
  unsigned short* lB = smem + 8192;
  const int z = blockIdx.z;
  const unsigned short* A = (z == 0) ? xq : (z == 1) ? xk : xv;
  const unsigned short* B = (z == 0) ? wq : (z == 1) ? wk : wv;
  const float* bias = (z == 0) ? bq : (z == 1) ? bk : bv;

  const int t = threadIdx.x;
  const int wid = t >> 6, lane = t & 63, lr = lane & 15, lg = lane >> 4;
  const int wm = wid >> 1, wn = wid & 1;
  const int m0 = blockIdx.y * 128, n0 = blockIdx.x * 128;
  const int K = DM;

  f32x4 acc[4][4] = {};

  for (int kb = 0; kb < K; kb += 64) {
    __syncthreads();
#pragma unroll
    for (int i = 0; i < 4; i++) {
      const int u = i * 256 + t;
      const int row = u >> 3;
      const int ke = (u & 7) * 8;
      unsigned short* la = lA + (size_t)(i * 256 + wid * 64) * 8;
      unsigned short* lb = lB + (size_t)(i * 256 + wid * 64) * 8;
      gl16(A + (size_t)(m0 + row) * K + kb + ke, la);
      gl16(B + (size_t)(n0 + row) * K + kb + ke, lb);
    }
    __syncthreads();
#pragma unroll
    for (int kk = 0; kk < 2; kk++) {
      bf16x8 af[4], bfr[4];
#pragma unroll
      for (int m = 0; m < 4; m++)
        af[m] = *reinterpret_cast<const bf16x8*>(&lA[(wm * 64 + m * 16 + lr) * 64 + kk * 32 + lg * 8]);
#pragma unroll
      for (int n = 0; n < 4; n++)
        bfr[n] = *reinterpret_cast<const bf16x8*>(&lB[(wn * 64 + n * 16 + lr) * 64 + kk * 32 + lg * 8]);
#pragma unroll
      for (int m = 0; m < 4; m++)
#pragma unroll
        for (int n = 0; n < 4; n++)
          acc[m][n] = mfma16(af[m], bfr[n], acc[m][n]);
    }
  }

  if (z < 2) {
    const float sc = (z == 0) ? 0.18033688f : 1.0f;  // 0.125 * log2(e) folded into Q
    unsigned short* dst = (z == 0) ? Qh : Kh;
#pragma unroll
    for (int m = 0; m < 4; m++)
#pragma unroll
      for (int n = 0; n < 4; n++) {
        const int col = n0 + wn * 64 + n * 16 + lr;
        const int hh = col >> 6, d = col & 63;
        const int row0 = m0 + wm * 64 + m * 16 + lg * 4;
        const float bsv = bias[col];
#pragma unroll
        for (int r = 0; r < 4; r++)
          dst[(size_t)hh * S64 + (size_t)(row0 + r) * HD + d] = f2bf((acc[m][n][r] + bsv) * sc);
      }
  } else {
    __syncthreads();
#pragma unroll
    for (int m = 0; m < 4; m++)
#pragma unroll
      for (int n = 0; n < 4; n++) {
        const int col = n0 + wn * 64 + n * 16 + lr;
        const int dt = wn * 64 + n * 16 + lr;  // d within tile
        const float bsv = bias[col];
#pragma unroll
        for (int r = 0; r < 4; r++) {
          const int st = wm * 64 + m * 16 + lg * 4 + r;  // s within tile
          smem[dt * 136 + st] = f2bf(acc[m][n][r] + bsv);
        }
      }
    __syncthreads();
#pragma unroll
    for (int it = 0; it < 8; it++) {
      const int u = it * 256 + t;
      const int d = u >> 4, sc8 = (u & 15) * 8;
      const int col = n0 + d, hh = col >> 6, dd = col & 63;
      *reinterpret_cast<uint4*>(VT + (size_t)hh * S64 + (size_t)dd * SQL + m0 + sc8) =
          *reinterpret_cast<const uint4*>(&smem[d * 136 + sc8]);
    }
  }
}

// ---------- final GEMM: out[M,N] fp32 = A[M,K] * B[N,K]^T + bias ----------
__global__ __launch_bounds__(256) void gemm_out(
    const unsigned short* __restrict__ A, const unsigned short* __restrict__ B,
    const float* __restrict__ bias, float* __restrict__ C) {
  __shared__ __align__(16) unsigned short lA[128 * 64];
  __shared__ __align__(16) unsigned short lB[128 * 64];
  const int t = threadIdx.x;
  const int wid = t >> 6, lane = t & 63, lr = lane & 15, lg = lane >> 4;
  const int wm = wid >> 1, wn = wid & 1;
  const int m0 = blockIdx.y * 128, n0 = blockIdx.x * 128;
  const int K = DM, N = DM;

  f32x4 acc[4][4] = {};

  for (int kb = 0; kb < K; kb += 64) {
    __syncthreads();
#pragma unroll
    for (int i = 0; i < 4; i++) {
      const int u = i * 256 + t;
      const int row = u >> 3;
      const int ke = (u & 7) * 8;
      unsigned short* la = lA + (size_t)(i * 256 + wid * 64) * 8;
      unsigned short* lb = lB + (size_t)(i * 256 + wid * 64) * 8;
      gl16(A + (size_t)(m0 + row) * K + kb + ke, la);
      gl16(B + (size_t)(n0 + row) * K + kb + ke, lb);
    }
    __syncthreads();
#pragma unroll
    for (int kk = 0; kk < 2; kk++) {
      bf16x8 af[4], bfr[4];
#pragma unroll
      for (int m = 0; m < 4; m++)
        af[m] = *reinterpret_cast<const bf16x8*>(&lA[(wm * 64 + m * 16 + lr) * 64 + kk * 32 + lg * 8]);
#pragma unroll
      for (int n = 0; n < 4; n++)
        bfr[n] = *reinterpret_cast<const bf16x8*>(&lB[(wn * 64 + n * 16 + lr) * 64 + kk * 32 + lg * 8]);
#pragma unroll
      for (int m = 0; m < 4; m++)
#pragma unroll
        for (int n = 0; n < 4; n++)
          acc[m][n] = mfma16(af[m], bfr[n], acc[m][n]);
    }
  }

#pragma unroll
  for (int m = 0; m < 4; m++)
#pragma unroll
    for (int n = 0; n < 4; n++)
#pragma unroll
      for (int r = 0; r < 4; r++) {
        const int row = m0 + wm * 64 + m * 16 + lg * 4 + r;
        const int col = n0 + wn * 64 + n * 16 + lr;
        C[(size_t)row * N + col] = acc[m][n][r] + bias[col];
      }
}

// ---------- causal flash attention: independent waves, no barriers ----------
// 1024 blocks x 128 threads = 2 INDEPENDENT waves. Wave wid owns 32-q tile
// T = wid ? 127-u : u  (u = bid>>4) -> every block = 129 KV-tile-units const.
// KVBLK=32. Per-wave LDS dbuf, reg-staged (T14): K rows 136B, V^T rows 72B
// (non-16B phases -> 2-way max bank aliasing), read as 2x ds_read_b64.
#define KB 32
#define KROW 136
#define VROW 72
#define VOFF (KB * KROW)           // 4352
#define BUFSZ (VOFF + HD * VROW)   // 8960
__global__ __launch_bounds__(128) void attn_fwd(
    const unsigned short* __restrict__ Qh, const unsigned short* __restrict__ Kh,
    const unsigned short* __restrict__ VT, unsigned short* __restrict__ Ob) {
  const int bid = blockIdx.x;
  const int h = bid & 15;
  const int u6 = bid >> 4;              // 0..63
  const int t = threadIdx.x;
  const int wid = t >> 6, lane = t & 63;
  const int ql = lane & 31, hi = lane >> 5;
  const int T = wid ? (127 - u6) : u6;  // 32-row q-tile index, pair-balanced
  const int q_g = T * 32 + ql;

  __shared__ __align__(16) char lds[2][2][BUFSZ];

  const unsigned short* Kp = Kh + (size_t)h * S64;
  const unsigned short* Vp = VT + (size_t)h * S64;

  // Q B-fragments: lane = col q, k-elems 16c + 8hi + j
  bf16x8 qf[4];
  {
    const unsigned short* qp = Qh + (size_t)h * S64 + (size_t)q_g * HD + hi * 8;
#pragma unroll
    for (int c = 0; c < 4; c++)
      qf[c] = *reinterpret_cast<const bf16x8*>(qp + c * 16);
  }

  f32x16 accO[2] = {};
  float m = -INFINITY, l = 0.f;
  const int ntile = T + 1;

  uint4 g[8];
  // ---- stage tile 0 ----
#pragma unroll
  for (int i = 0; i < 4; i++) {
    const int v = i * 64 + lane, r = v >> 3, p = v & 7;
    g[i] = *(const uint4*)(Kp + (size_t)r * HD + p * 8);
  }
#pragma unroll
  for (int i = 0; i < 4; i++) {
    const int v = i * 64 + lane, r = v >> 2, p = v & 3;
    g[4 + i] = *(const uint4*)(Vp + (size_t)r * SQL + p * 8);
  }
  {
    char* d0 = &lds[wid][0][0];
#pragma unroll
    for (int i = 0; i < 4; i++) {
      const int v = i * 64 + lane, r = v >> 3, p = v & 7;
      char* d = d0 + r * KROW + p * 16;
      *(uint2*)d = make_uint2(g[i].x, g[i].y);
      *(uint2*)(d + 8) = make_uint2(g[i].z, g[i].w);
    }
#pragma unroll
    for (int i = 0; i < 4; i++) {
      const int v = i * 64 + lane, r = v >> 2, p = v & 3;
      char* d = d0 + VOFF + r * VROW + p * 16;
      *(uint2*)d = make_uint2(g[4 + i].x, g[4 + i].y);
      *(uint2*)(d + 8) = make_uint2(g[4 + i].z, g[4 + i].w);
    }
  }

  int cur = 0;
  for (int tk = 0; tk < ntile; tk++) {
    const int kv0 = tk * KB;
    const bool pre = (tk + 1 < ntile);
    // ---- issue loads for tile tk+1 (hidden under compute) ----
    if (pre) {
      const int nkv = kv0 + KB;
#pragma unroll
      for (int i = 0; i < 4; i++) {
        const int v = i * 64 + lane, r = v >> 3, p = v & 7;
        g[i] = *(const uint4*)(Kp + (size_t)(nkv + r) * HD + p * 8);
      }
#pragma unroll
      for (int i = 0; i < 4; i++) {
        const int v = i * 64 + lane, r = v >> 2, p = v & 3;
        g[4 + i] = *(const uint4*)(Vp + (size_t)r * SQL + nkv + p * 8);
      }
    }

    const char* kb = &lds[wid][cur][0];

    // ---- QK^T swapped: sA = S^T[kv=crow(r,hi)][q=ql] ----
    f32x16 sA = {};
    __builtin_amdgcn_s_setprio(1);
#pragma unroll
    for (int c = 0; c < 4; c++) {
      bf16x8 kf = ld_b64x2(kb + ql * KROW + (2 * c + hi) * 16);
      sA = mfma32(kf, qf[c], sA);
    }
    __builtin_amdgcn_s_setprio(0);

    // causal mask (diagonal tile only)
    if (tk == T) {
#pragma unroll
      for (int r = 0; r < 16; r++) {
        const int kv_g = kv0 + (r & 3) + 8 * (r >> 2) + 4 * hi;
        if (kv_g > q_g) sA[r] = -INFINITY;
      }
    }

    // ---- online softmax (exp2 domain), defer-max THR=8 ----
    float m0a = fmaxf(sA[0], sA[1]), m1a = fmaxf(sA[2], sA[3]);
    float m2a = fmaxf(sA[4], sA[5]), m3a = fmaxf(sA[6], sA[7]);
    float m4a = fmaxf(sA[8], sA[9]), m5a = fmaxf(sA[10], sA[11]);
    float m6a = fmaxf(sA[12], sA[13]), m7a = fmaxf(sA[14], sA[15]);
    float pm = fmaxf(fmaxf(fmaxf(m0a, m1a), fmaxf(m2a, m3a)),
                     fmaxf(fmaxf(m4a, m5a), fmaxf(m6a, m7a)));
    pm = fmaxf(pm, __shfl_xor(pm, 32));
    if (!__all(pm - m <= 8.f)) {
      const float mn = fmaxf(m, pm);
      const float al = exp2f(m - mn);
      m = mn;
      l *= al;
#pragma unroll
      for (int dc = 0; dc < 2; dc++)
#pragma unroll
        for (int r = 0; r < 16; r++) accO[dc][r] *= al;
    }
    float sum = 0.f;
#pragma unroll
    for (int r = 0; r < 16; r++) {
      const float e = exp2f(sA[r] - m);
      sA[r] = e;
      sum += e;
    }
    sum += __shfl_xor(sum, 32);
    l += sum;

    // ---- pack P^T into PV B-fragments (cross-lane ^32 exchange) ----
    // B-frag needs kv = 16ck + 8hi + j. Own regs hold kv = {0..3,8..11,16..19,
    // 24..27} + 4hi. hi=0: own->j0..3, rcv->j4..7. hi=1: rcv->j0..3, own->j4..7.
    bf16x8 pf[2];
#pragma unroll
    for (int ck = 0; ck < 2; ck++) {
      const int bo = (2 * ck + hi) << 2;        // keep base (own quad)
      const int bs = (2 * ck + (1 - hi)) << 2;  // send base (partner's quad)
      unsigned own0 = cvtpk(sA[bo + 0], sA[bo + 1]);
      unsigned own1 = cvtpk(sA[bo + 2], sA[bo + 3]);
      unsigned snd0 = cvtpk(sA[bs + 0], sA[bs + 1]);
      unsigned snd1 = cvtpk(sA[bs + 2], sA[bs + 3]);
      unsigned rcv0 = (unsigned)__shfl_xor((int)snd0, 32);
      unsigned rcv1 = (unsigned)__shfl_xor((int)snd1, 32);
      unsigned* pw = (unsigned*)&pf[ck];
      pw[0] = hi ? rcv0 : own0;
      pw[1] = hi ? rcv1 : own1;
      pw[2] = hi ? own0 : rcv0;
      pw[3] = hi ? own1 : rcv1;
    }

    // ---- PV swapped: accO[dc] += V^T[32dc+crow][kv] * P^T[kv][q] ----
    __builtin_amdgcn_s_setprio(1);
#pragma unroll
    for (int dc = 0; dc < 2; dc++) {
#pragma unroll
      for (int ck = 0; ck < 2; ck++) {
        bf16x8 vf = ld_b64x2(kb + VOFF + (32 * dc + ql) * VROW + (2 * ck + hi) * 16);
        accO[dc] = mfma32(vf, pf[ck], accO[dc]);
      }
    }
    __builtin_amdgcn_s_setprio(0);

    // ---- write tile tk+1 into the other buffer ----
    if (pre) {
      char* d0 = &lds[wid][cur ^ 1][0];
#pragma unroll
      for (int i = 0; i < 4; i++) {
        const int v = i * 64 + lane, r = v >> 3, p = v & 7;
        char* d = d0 + r * KROW + p * 16;
        *(uint2*)d = make_uint2(g[i].x, g[i].y);
        *(uint2*)(d + 8) = make_uint2(g[i].z, g[i].w);
      }
#pragma unroll
      for (int i = 0; i < 4; i++) {
        const int v = i * 64 + lane, r = v >> 2, p = v & 3;
        char* d = d0 + VOFF + r * VROW + p * 16;
        *(uint2*)d = make_uint2(g[4 + i].x, g[4 + i].y);
        *(uint2*)(d + 8) = make_uint2(g[4 + i].z, g[4 + i].w);
      }
    }
    cur ^= 1;
  }

  // ---- normalize + store ----
  const float inv = 1.f / l;
  unsigned short* ob = Ob + (size_t)q_g * DM + h * HD;
#pragma unroll
  for (int dc = 0; dc < 2; dc++)
#pragma unroll
    for (int tq = 0; tq < 4; tq++) {
      ushort4 o;
      o.x = f2bf(accO[dc][tq * 4 + 0] * inv);
      o.y = f2bf(accO[dc][tq * 4 + 1] * inv);
      o.z = f2bf(accO[dc][tq * 4 + 2] * inv);
      o.w = f2bf(accO[dc][tq * 4 + 3] * inv);
      *reinterpret_cast<ushort4*>(ob + dc * 32 + tq * 8 + hi * 4) = o;
    }
}

// ---------- launch ----------
extern "C" void kernel_launch(void* const* d_in, const int* in_sizes, int n_in,
                              void* d_out, int out_size, void* d_ws, size_t ws_size,
                              hipStream_t stream) {
  const float* queries = (const float*)d_in[0];
  const float* keys    = (const float*)d_in[1];
  const float* values  = (const float*)d_in[2];
  const float* Wq = (const float*)d_in[3];
  const float* bq = (const float*)d_in[4];
  const float* Wk = (const float*)d_in[5];
  const float* bk = (const float*)d_in[6];
  const float* Wv = (const float*)d_in[7];
  const float* bv = (const float*)d_in[8];
  const float* Wo = (const float*)d_in[9];
  const float* bo = (const float*)d_in[10];
  float* out = (float*)d_out;

  const size_t SD = (size_t)SQL * DM;
  const size_t DD = (size_t)DM * DM;

  unsigned short* p = (unsigned short*)d_ws;
  unsigned short* xq = p; p += SD;
  unsigned short* xk = p; p += SD;
  unsigned short* xv = p; p += SD;
  unsigned short* wq = p; p += DD;
  unsigned short* wk = p; p += DD;
  unsigned short* wv = p; p += DD;
  unsigned short* wo = p; p += DD;
  unsigned short* Qh = p; p += SD;   // [h][s][64], pre-scaled
  unsigned short* Kh = p; p += SD;   // [h][s][64]
  unsigned short* VTg = p; p += SD;  // [h][64][s]
  unsigned short* Ob = xq;           // alias: xq dead after QKV GEMM

  const int ncvt = (int)((3 * SD + 4 * DD) / 1024);
  cvt_all<<<ncvt, 256, 0, stream>>>(queries, keys, values, Wq, Wk, Wv, Wo, xq);

  gemm_qkv<<<dim3(DM / 128, SQL / 128, 3), 256, 0, stream>>>(
      xq, xk, xv, wq, wk, wv, bq, bk, bv, Qh, Kh, VTg);

  attn_fwd<<<1024, 128, 0, stream>>>(Qh, Kh, VTg, Ob);

  gemm_out<<<dim3(DM / 128, SQL / 128), 256, 0, stream>>>(Ob, wo, bo, out);
}